// Round 2
// 877.799 us; speedup vs baseline: 1.7994x; 1.7994x over previous
//
#include <hip/hip_runtime.h>

typedef unsigned short ushort_t;
typedef unsigned int uint_t;
typedef __attribute__((ext_vector_type(8))) short bf16x8;   // 8 bf16 = 4 VGPR
typedef __attribute__((ext_vector_type(4))) float f32x4;    // MFMA C/D

#define B_SZ 2048
#define C_SZ 100
#define P_SZ 128
#define D_SZ 192

// LDS row strides (elements). Row stride in 16B quads must be odd (mod 8) so that
// 16-consecutive-row b128 fragment reads are 2-way (free) on the 32 banks.
#define XET_S 136   // ushort, 272 B = 17 quads
#define Y_S   196   // u32,    784 B = 49 quads
#define SM_S  132   // f32,    528 B
#define MB_S  136   // ushort, 272 B

#define MFMA16 __builtin_amdgcn_mfma_f32_16x16x32_bf16

// ---- batch-independent tables as device globals: NO workspace dependency ----
__device__ ushort_t g_colb_hi[P_SZ * D_SZ];   // LN(emb_column) hi, rows [100,128) zero
__device__ ushort_t g_colb_lo[P_SZ * D_SZ];   // LN(emb_column) lo
__device__ float    g_cp[P_SZ * D_SZ];        // LN(emb_prompt)@W1 + b_imp + emb_prompt
__device__ ushort_t g_w2t_hi[D_SZ * D_SZ];    // W2^T hi: [d][e], e(K)-contiguous
__device__ ushort_t g_w2t_lo[D_SZ * D_SZ];    // W2^T lo

__device__ __forceinline__ float b2f(ushort_t u) {
    union { uint_t i; float f; } v; v.i = ((uint_t)u) << 16; return v.f;
}
__device__ __forceinline__ ushort_t f2b(float f) {
    uint_t x = __float_as_uint(f);
    uint_t r = x + 0x7fffu + ((x >> 16) & 1u);  // RNE
    return (ushort_t)(r >> 16);
}

// ---------------- K0: batch-independent precompute ----------------
// blocks [0,100)   : g_colb_hi/lo[c][d] = split(LN(emb_column[c,:]))
// blocks [100,128) : g_colb pad rows -> 0
// blocks [128,256) : g_cp[p][d] = LN(emb_prompt[p]) @ W_imp[0:192,:] + b_imp + emb_prompt[p]
// blocks [256,448) : g_w2t_hi/lo[d][e] = split(W_imp[192+e][d])
__global__ __launch_bounds__(192) void precompute(
    const float* __restrict__ emb_column, const float* __restrict__ emb_prompt,
    const float* __restrict__ ln_col_w, const float* __restrict__ ln_col_b,
    const float* __restrict__ ln_prompt_w, const float* __restrict__ ln_prompt_b,
    const float* __restrict__ W_imp, const float* __restrict__ b_imp)
{
    const int r = blockIdx.x;
    const int t = threadIdx.x;            // 0..191
    const int wid = t >> 6, lane = t & 63;
    __shared__ float redS[3], redQ[3];
    __shared__ float rowv[D_SZ];

    if (r < C_SZ) {
        float v = emb_column[r * D_SZ + t];
        float s = v, q = v * v;
        #pragma unroll
        for (int o = 1; o < 64; o <<= 1) { s += __shfl_xor(s, o); q += __shfl_xor(q, o); }
        if (lane == 0) { redS[wid] = s; redQ[wid] = q; }
        __syncthreads();
        s = redS[0] + redS[1] + redS[2];
        q = redQ[0] + redQ[1] + redQ[2];
        float m = s * (1.f / D_SZ);
        float var = fmaxf(q * (1.f / D_SZ) - m * m, 0.f);
        float rs = rsqrtf(var + 1e-5f);
        float o = (v - m) * rs * ln_col_w[t] + ln_col_b[t];
        ushort_t h = f2b(o);
        g_colb_hi[r * D_SZ + t] = h;
        g_colb_lo[r * D_SZ + t] = f2b(o - b2f(h));
    } else if (r < P_SZ) {
        g_colb_hi[r * D_SZ + t] = 0;
        g_colb_lo[r * D_SZ + t] = 0;
    } else if (r < 2 * P_SZ) {
        const int p = r - P_SZ;
        float v = emb_prompt[p * D_SZ + t];
        float s = v, q = v * v;
        #pragma unroll
        for (int o = 1; o < 64; o <<= 1) { s += __shfl_xor(s, o); q += __shfl_xor(q, o); }
        if (lane == 0) { redS[wid] = s; redQ[wid] = q; }
        __syncthreads();
        s = redS[0] + redS[1] + redS[2];
        q = redQ[0] + redQ[1] + redQ[2];
        float m = s * (1.f / D_SZ);
        float var = fmaxf(q * (1.f / D_SZ) - m * m, 0.f);
        float rs = rsqrtf(var + 1e-5f);
        rowv[t] = (v - m) * rs * ln_prompt_w[t] + ln_prompt_b[t];
        __syncthreads();
        float a = b_imp[t] + v;           // residual p0
        for (int e = 0; e < D_SZ; ++e)
            a = fmaf(rowv[e], W_imp[e * D_SZ + t], a);
        g_cp[p * D_SZ + t] = a;
    } else {
        const int d = r - 2 * P_SZ;
        float wv = W_imp[(D_SZ + t) * D_SZ + d];   // W2[e=t][d]
        ushort_t h = f2b(wv);
        g_w2t_hi[d * D_SZ + t] = h;
        g_w2t_lo[d * D_SZ + t] = f2b(wv - b2f(h));
    }
}

// ---------------- K1: per-batch fused, MFMA-based ----------------
// 512 threads = 8 waves per block, one block per batch. P in 2 chunks of 64.
__global__ __launch_bounds__(512) void fused(
    const float* __restrict__ x, const float* __restrict__ prev,
    const float* __restrict__ wfe, const float* __restrict__ bfe,
    const float* __restrict__ lnw, const float* __restrict__ lnb,
    const float* __restrict__ wexp, const float* __restrict__ bexp,
    float* __restrict__ out)
{
    __shared__ __align__(16) ushort_t xeT[D_SZ * XET_S];   // 52224 B: x_emb^T [d][c]
    __shared__ __align__(16) uint_t   ylds[64 * Y_S];      // 50176 B: y packed (hi<<16)|lo
    __shared__ __align__(16) ushort_t maskb[64 * MB_S];    // 17408 B: softmax mask bf16
    float* smat = (float*)ylds;     // overlay: fp32 scores [64][SM_S]

    const int b    = blockIdx.x;
    const int tid  = threadIdx.x;
    const int w    = tid >> 6;
    const int l    = tid & 63;
    const int l15  = l & 15;
    const int koff = (l >> 4) * 8;
    const size_t bP = (size_t)b * P_SZ;
    const f32x4 fzero = {0.f, 0.f, 0.f, 0.f};

    // ---- stage 0: x_emb^T = LN(relu(x*wfe+bfe))^T -> xeT[d][c] (bf16, c-contig) ----
    {
        const float lw0 = lnw[l],       lb0 = lnb[l];
        const float lw1 = lnw[l + 64],  lb1 = lnb[l + 64];
        const float lw2 = lnw[l + 128], lb2 = lnb[l + 128];
        for (int c = w; c < C_SZ; c += 8) {           // wave-per-column
            const float xv = x[b * C_SZ + c];
            const float* wr = wfe + c * D_SZ;
            const float* br = bfe + c * D_SZ;
            float v0 = fmaxf(fmaf(xv, wr[l],       br[l]),       0.f);
            float v1 = fmaxf(fmaf(xv, wr[l + 64],  br[l + 64]),  0.f);
            float v2 = fmaxf(fmaf(xv, wr[l + 128], br[l + 128]), 0.f);
            float s = v0 + v1 + v2;
            float q = v0 * v0 + v1 * v1 + v2 * v2;
            #pragma unroll
            for (int o = 1; o < 64; o <<= 1) { s += __shfl_xor(s, o); q += __shfl_xor(q, o); }
            const float m   = s * (1.f / D_SZ);
            const float var = fmaxf(q * (1.f / D_SZ) - m * m, 0.f);
            const float rs  = rsqrtf(var + 1e-5f);
            xeT[l * XET_S + c]         = f2b((v0 - m) * rs * lw0 + lb0);
            xeT[(l + 64) * XET_S + c]  = f2b((v1 - m) * rs * lw1 + lb1);
            xeT[(l + 128) * XET_S + c] = f2b((v2 - m) * rs * lw2 + lb2);
        }
        // zero-pad columns c in [100,128) (K-pad for G3)
        for (int idx = tid; idx < D_SZ * 28; idx += 512)
            xeT[(idx / 28) * XET_S + C_SZ + (idx % 28)] = 0;
    }
    __syncthreads();

    for (int chunk = 0; chunk < 2; ++chunk) {
        const int pbase = chunk * 64;

        // ---- G1: y[64][192] = prev_chunk @ W2 (+cp), hi/lo split bf16 MFMA ----
        {
            const int wm = w >> 2, wn = w & 3;    // 2 x 4 wave grid: M=32/wave, N=48/wave
            f32x4 acc[2][3];
            #pragma unroll
            for (int mt = 0; mt < 2; ++mt) {
                #pragma unroll
                for (int nt = 0; nt < 3; ++nt) acc[mt][nt] = fzero;
            }
            const int arow = pbase + 32 * wm + l15;
            for (int kt = 0; kt < 6; ++kt) {
                const int e0 = kt * 32 + koff;
                bf16x8 ah[2], al[2];
                #pragma unroll
                for (int mt = 0; mt < 2; ++mt) {
                    const float* ap = prev + (bP + (size_t)(arow + 16 * mt)) * D_SZ + e0;
                    const float4 v0 = *(const float4*)ap;
                    const float4 v1 = *(const float4*)(ap + 4);
                    const float av[8] = {v0.x, v0.y, v0.z, v0.w, v1.x, v1.y, v1.z, v1.w};
                    #pragma unroll
                    for (int j = 0; j < 8; ++j) {
                        const ushort_t h = f2b(av[j]);
                        ah[mt][j] = (short)h;
                        al[mt][j] = (short)f2b(av[j] - b2f(h));
                    }
                }
                #pragma unroll
                for (int nt = 0; nt < 3; ++nt) {
                    const int drow = 48 * wn + 16 * nt + l15;
                    const bf16x8 bh = *(const bf16x8*)(g_w2t_hi + drow * D_SZ + e0);
                    const bf16x8 bl = *(const bf16x8*)(g_w2t_lo + drow * D_SZ + e0);
                    #pragma unroll
                    for (int mt = 0; mt < 2; ++mt) {
                        acc[mt][nt] = MFMA16(ah[mt], bh, acc[mt][nt], 0, 0, 0);
                        acc[mt][nt] = MFMA16(al[mt], bh, acc[mt][nt], 0, 0, 0);
                        acc[mt][nt] = MFMA16(ah[mt], bl, acc[mt][nt], 0, 0, 0);
                    }
                }
            }
            // epilogue: +cp, split hi/lo, pack into ylds
            const int pr0 = 32 * wm + 4 * (l >> 4);
            #pragma unroll
            for (int mt = 0; mt < 2; ++mt) {
                #pragma unroll
                for (int nt = 0; nt < 3; ++nt) {
                    const int d = 48 * wn + 16 * nt + l15;
                    #pragma unroll
                    for (int r = 0; r < 4; ++r) {
                        const int pl = pr0 + 16 * mt + r;
                        const float y = acc[mt][nt][r] + g_cp[(pbase + pl) * D_SZ + d];
                        const ushort_t h  = f2b(y);
                        const ushort_t lo = f2b(y - b2f(h));
                        ylds[pl * Y_S + d] = ((uint_t)h << 16) | (uint_t)lo;
                    }
                }
            }
        }
        __syncthreads();

        // ---- G2: s[64][128] = y @ col^T, hi/lo split both operands ----
        {
            const int wm2 = w >> 1, wn2 = w & 1;   // 4 x 2 wave grid: M=16/wave, N=64/wave
            f32x4 sacc[4];
            #pragma unroll
            for (int nt = 0; nt < 4; ++nt) sacc[nt] = fzero;
            const int prow = 16 * wm2 + l15;
            for (int kt = 0; kt < 6; ++kt) {
                const int dk = kt * 32 + koff;
                const uint_t* yp = ylds + prow * Y_S + dk;
                const uint4 u0 = *(const uint4*)yp;
                const uint4 u1 = *(const uint4*)(yp + 4);
                const uint_t uu[8] = {u0.x, u0.y, u0.z, u0.w, u1.x, u1.y, u1.z, u1.w};
                bf16x8 ah, al;
                #pragma unroll
                for (int j = 0; j < 8; ++j) {
                    ah[j] = (short)(uu[j] >> 16);
                    al[j] = (short)(uu[j] & 0xffffu);
                }
                #pragma unroll
                for (int nt = 0; nt < 4; ++nt) {
                    const int crow = 64 * wn2 + 16 * nt + l15;
                    const bf16x8 bh = *(const bf16x8*)(g_colb_hi + crow * D_SZ + dk);
                    const bf16x8 bl = *(const bf16x8*)(g_colb_lo + crow * D_SZ + dk);
                    sacc[nt] = MFMA16(ah, bh, sacc[nt], 0, 0, 0);
                    sacc[nt] = MFMA16(al, bh, sacc[nt], 0, 0, 0);
                    sacc[nt] = MFMA16(ah, bl, sacc[nt], 0, 0, 0);
                }
            }
            __syncthreads();   // all ylds reads done before overwriting as smat
            const int pr0 = 16 * wm2 + 4 * (l >> 4);
            #pragma unroll
            for (int nt = 0; nt < 4; ++nt) {
                const int cc = 64 * wn2 + 16 * nt + l15;
                #pragma unroll
                for (int r = 0; r < 4; ++r)
                    smat[(pr0 + r) * SM_S + cc] = sacc[nt][r];
            }
        }
        __syncthreads();

        // ---- softmax over c (8 rows/wave) -> maskb bf16, pad c>=100 to 0 ----
        {
            #pragma unroll
            for (int i = 0; i < 8; ++i) {
                const int p = w * 8 + i;
                const float s0 = smat[p * SM_S + l];
                const bool c1ok = (l < C_SZ - 64);
                const float s1 = c1ok ? smat[p * SM_S + 64 + l] : -3.0e38f;
                float mx = fmaxf(s0, s1);
                #pragma unroll
                for (int o = 1; o < 64; o <<= 1) mx = fmaxf(mx, __shfl_xor(mx, o));
                const float e0 = __expf(s0 - mx);
                const float e1 = c1ok ? __expf(s1 - mx) : 0.f;
                float ts = e0 + e1;
                #pragma unroll
                for (int o = 1; o < 64; o <<= 1) ts += __shfl_xor(ts, o);
                const float inv = 1.f / ts;
                maskb[p * MB_S + l] = f2b(e0 * inv);
                maskb[p * MB_S + 64 + l] = c1ok ? f2b(e1 * inv) : (ushort_t)0;
            }
        }
        __syncthreads();

        // ---- G3: agg[64][192] = mask @ x_emb (K=128 padded), + epilogue store ----
        {
            const int wm3 = w >> 2, wn3 = w & 3;   // 2 x 4 wave grid
            f32x4 acc[2][3];
            #pragma unroll
            for (int mt = 0; mt < 2; ++mt) {
                #pragma unroll
                for (int nt = 0; nt < 3; ++nt) acc[mt][nt] = fzero;
            }
            const int arow = 32 * wm3 + l15;
            for (int kt = 0; kt < 4; ++kt) {
                const int c0 = kt * 32 + koff;
                const bf16x8 a0 = *(const bf16x8*)(maskb + arow * MB_S + c0);
                const bf16x8 a1 = *(const bf16x8*)(maskb + (arow + 16) * MB_S + c0);
                #pragma unroll
                for (int nt = 0; nt < 3; ++nt) {
                    const int d = 48 * wn3 + 16 * nt + l15;
                    const bf16x8 bx = *(const bf16x8*)(xeT + d * XET_S + c0);
                    acc[0][nt] = MFMA16(a0, bx, acc[0][nt], 0, 0, 0);
                    acc[1][nt] = MFMA16(a1, bx, acc[1][nt], 0, 0, 0);
                }
            }
            const int pr0 = pbase + 32 * wm3 + 4 * (l >> 4);
            #pragma unroll
            for (int mt = 0; mt < 2; ++mt) {
                #pragma unroll
                for (int r = 0; r < 4; ++r) {
                    const int p = pr0 + 16 * mt + r;
                    const float sc = 1.f + wexp[p];
                    const float bi = bexp[p];
                    float* orow = out + (bP + p) * D_SZ;
                    #pragma unroll
                    for (int nt = 0; nt < 3; ++nt) {
                        const int d = 48 * wn3 + 16 * nt + l15;
                        orow[d] = fmaf(acc[mt][nt][r], sc, bi);
                    }
                }
            }
        }
        __syncthreads();   // protect ylds/maskb for next chunk
    }
}

extern "C" void kernel_launch(void* const* d_in, const int* in_sizes, int n_in,
                              void* d_out, int out_size, void* d_ws, size_t ws_size,
                              hipStream_t stream) {
    const float* x           = (const float*)d_in[0];
    const float* prev        = (const float*)d_in[1];
    const float* wfe         = (const float*)d_in[2];
    const float* bfe         = (const float*)d_in[3];
    const float* ln_emb_w    = (const float*)d_in[4];
    const float* ln_emb_b    = (const float*)d_in[5];
    const float* ln_col_w    = (const float*)d_in[6];
    const float* ln_col_b    = (const float*)d_in[7];
    const float* ln_prompt_w = (const float*)d_in[8];
    const float* ln_prompt_b = (const float*)d_in[9];
    const float* W_imp       = (const float*)d_in[10];
    const float* b_imp       = (const float*)d_in[11];
    const float* emb_column  = (const float*)d_in[12];
    const float* emb_prompt  = (const float*)d_in[13];
    const float* wexp        = (const float*)d_in[14];
    const float* bexp        = (const float*)d_in[15];
    float* out = (float*)d_out;
    (void)d_ws; (void)ws_size;

    precompute<<<2 * P_SZ + D_SZ, 192, 0, stream>>>(emb_column, emb_prompt,
        ln_col_w, ln_col_b, ln_prompt_w, ln_prompt_b, W_imp, b_imp);
    fused<<<B_SZ, 512, 0, stream>>>(x, prev, wfe, bfe, ln_emb_w, ln_emb_b,
        wexp, bexp, out);
}

// Round 3
// 826.164 us; speedup vs baseline: 1.9119x; 1.0625x over previous
//
#include <hip/hip_runtime.h>

typedef unsigned short ushort_t;
typedef unsigned int uint_t;
typedef __attribute__((ext_vector_type(8))) short bf16x8;   // 8 bf16 = 4 VGPR
typedef __attribute__((ext_vector_type(4))) float f32x4;    // MFMA C/D

#define B_SZ 2048
#define C_SZ 100
#define P_SZ 128
#define D_SZ 192
#define CH   32     // prompts per chunk
#define NCH  4      // chunks (P_SZ / CH)

#define MFMA16 __builtin_amdgcn_mfma_f32_16x16x32_bf16

// ---- batch-independent tables as device globals (no workspace dependency) ----
__device__ ushort_t g_colb_hi[P_SZ * D_SZ];   // LN(emb_column) hi, rows [100,128) zero
__device__ ushort_t g_colb_lo[P_SZ * D_SZ];   // LN(emb_column) lo
__device__ float    g_cp[P_SZ * D_SZ];        // LN(emb_prompt)@W1 + b_imp + emb_prompt
__device__ ushort_t g_w2t_hi[D_SZ * D_SZ];    // W2^T hi: [d][e], e(K)-contiguous
__device__ ushort_t g_w2t_lo[D_SZ * D_SZ];    // W2^T lo

__device__ __forceinline__ float b2f(ushort_t u) {
    union { uint_t i; float f; } v; v.i = ((uint_t)u) << 16; return v.f;
}
__device__ __forceinline__ ushort_t f2b(float f) {
    uint_t x = __float_as_uint(f);
    uint_t r = x + 0x7fffu + ((x >> 16) & 1u);  // RNE
    return (ushort_t)(r >> 16);
}
__device__ __forceinline__ uint_t packhl(float f) {   // (hi<<16)|lo split-bf16
    const ushort_t h = f2b(f);
    const ushort_t lo = f2b(f - b2f(h));
    return ((uint_t)h << 16) | (uint_t)lo;
}

// ---- XOR quad-swizzled LDS index helpers (power-of-2 rows, conflict-tamed) ----
__device__ __forceinline__ int xet_off(int d, int c) {   // ushort idx, row=128 us
    return d * 128 + ((((c >> 3) ^ ((d & 7) << 1)) << 3) | (c & 7));
}
__device__ __forceinline__ int mb_off(int p, int c) {    // ushort idx, row=128 us
    return p * 128 + ((((c >> 3) ^ ((p & 7) << 1)) << 3) | (c & 7));
}
__device__ __forceinline__ int y_off(int r, int col) {   // u32 idx, row=192 u32
    return r * 192 + ((((col >> 2) ^ ((r & 7) << 1)) << 2) | (col & 3));
}

// ---------------- K0: batch-independent precompute ----------------
// blocks [0,100)   : g_colb_hi/lo[c][d] = split(LN(emb_column[c,:]))
// blocks [100,128) : g_colb pad rows -> 0
// blocks [128,256) : g_cp[p][d] = LN(emb_prompt[p]) @ W_imp[0:192,:] + b_imp + emb_prompt[p]
// blocks [256,304) : g_w2t_hi/lo[d0..d0+3][e] = split(W_imp[192+e][d0..d0+3])
__global__ __launch_bounds__(192) void precompute(
    const float* __restrict__ emb_column, const float* __restrict__ emb_prompt,
    const float* __restrict__ ln_col_w, const float* __restrict__ ln_col_b,
    const float* __restrict__ ln_prompt_w, const float* __restrict__ ln_prompt_b,
    const float* __restrict__ W_imp, const float* __restrict__ b_imp)
{
    const int r = blockIdx.x;
    const int t = threadIdx.x;            // 0..191
    const int wid = t >> 6, lane = t & 63;
    __shared__ float redS[3], redQ[3];
    __shared__ float rowv[D_SZ];

    if (r < C_SZ) {
        float v = emb_column[r * D_SZ + t];
        float s = v, q = v * v;
        #pragma unroll
        for (int o = 1; o < 64; o <<= 1) { s += __shfl_xor(s, o); q += __shfl_xor(q, o); }
        if (lane == 0) { redS[wid] = s; redQ[wid] = q; }
        __syncthreads();
        s = redS[0] + redS[1] + redS[2];
        q = redQ[0] + redQ[1] + redQ[2];
        float m = s * (1.f / D_SZ);
        float var = fmaxf(q * (1.f / D_SZ) - m * m, 0.f);
        float rs = rsqrtf(var + 1e-5f);
        float o = (v - m) * rs * ln_col_w[t] + ln_col_b[t];
        ushort_t h = f2b(o);
        g_colb_hi[r * D_SZ + t] = h;
        g_colb_lo[r * D_SZ + t] = f2b(o - b2f(h));
    } else if (r < P_SZ) {
        g_colb_hi[r * D_SZ + t] = 0;
        g_colb_lo[r * D_SZ + t] = 0;
    } else if (r < 2 * P_SZ) {
        const int p = r - P_SZ;
        float v = emb_prompt[p * D_SZ + t];
        float s = v, q = v * v;
        #pragma unroll
        for (int o = 1; o < 64; o <<= 1) { s += __shfl_xor(s, o); q += __shfl_xor(q, o); }
        if (lane == 0) { redS[wid] = s; redQ[wid] = q; }
        __syncthreads();
        s = redS[0] + redS[1] + redS[2];
        q = redQ[0] + redQ[1] + redQ[2];
        float m = s * (1.f / D_SZ);
        float var = fmaxf(q * (1.f / D_SZ) - m * m, 0.f);
        float rs = rsqrtf(var + 1e-5f);
        rowv[t] = (v - m) * rs * ln_prompt_w[t] + ln_prompt_b[t];
        __syncthreads();
        float a0 = 0.f, a1 = 0.f, a2 = 0.f, a3 = 0.f;   // ILP unroll
        for (int e = 0; e < D_SZ; e += 4) {
            a0 = fmaf(rowv[e + 0], W_imp[(e + 0) * D_SZ + t], a0);
            a1 = fmaf(rowv[e + 1], W_imp[(e + 1) * D_SZ + t], a1);
            a2 = fmaf(rowv[e + 2], W_imp[(e + 2) * D_SZ + t], a2);
            a3 = fmaf(rowv[e + 3], W_imp[(e + 3) * D_SZ + t], a3);
        }
        g_cp[p * D_SZ + t] = b_imp[t] + v + ((a0 + a1) + (a2 + a3));
    } else {
        const int d0 = (r - 2 * P_SZ) * 4;
        const float4 wv = *(const float4*)(W_imp + (D_SZ + t) * D_SZ + d0);
        const float vv[4] = {wv.x, wv.y, wv.z, wv.w};
        #pragma unroll
        for (int j = 0; j < 4; ++j) {
            const ushort_t h = f2b(vv[j]);
            g_w2t_hi[(d0 + j) * D_SZ + t] = h;
            g_w2t_lo[(d0 + j) * D_SZ + t] = f2b(vv[j] - b2f(h));
        }
    }
}

// ---------------- K1: per-batch fused, MFMA-based ----------------
// 512 threads = 8 waves, one block per batch; P in 4 chunks of 32.
// LDS 72KB -> 2 blocks/CU. ylds buffer multiplexed: staged prev -> y -> smat/maskb.
__global__ __launch_bounds__(512, 4) void fused(
    const float* __restrict__ x, const float* __restrict__ prev,
    const float* __restrict__ wfe, const float* __restrict__ bfe,
    const float* __restrict__ lnw, const float* __restrict__ lnb,
    const float* __restrict__ wexp, const float* __restrict__ bexp,
    float* __restrict__ out)
{
    __shared__ __align__(16) ushort_t xeT[D_SZ * 128];   // 49152 B: x_emb^T [d][c] swizzled
    __shared__ __align__(16) uint_t   ylds[CH * D_SZ];   // 24576 B: prev-packed / y-packed
    float*    smat  = (float*)ylds;                       // overlay [32][128] f32 (16384 B)
    ushort_t* maskb = (ushort_t*)((char*)ylds + 16384);   // overlay [32][128] bf16 (8192 B)

    const int b    = blockIdx.x;
    const int tid  = threadIdx.x;
    const int w    = tid >> 6;
    const int l    = tid & 63;
    const int l15  = l & 15;
    const int koff = (l >> 4) * 8;
    const size_t bP = (size_t)b * P_SZ;
    const f32x4 fzero = {0.f, 0.f, 0.f, 0.f};

    // ---- stage 0: x_emb^T = LN(relu(x*wfe+bfe))^T -> xeT[d][c] (bf16, swizzled) ----
    {
        const float lw0 = lnw[l],       lb0 = lnb[l];
        const float lw1 = lnw[l + 64],  lb1 = lnb[l + 64];
        const float lw2 = lnw[l + 128], lb2 = lnb[l + 128];
        for (int c = w; c < C_SZ; c += 8) {           // wave-per-column
            const float xv = x[b * C_SZ + c];
            const float* wr = wfe + c * D_SZ;
            const float* br = bfe + c * D_SZ;
            float v0 = fmaxf(fmaf(xv, wr[l],       br[l]),       0.f);
            float v1 = fmaxf(fmaf(xv, wr[l + 64],  br[l + 64]),  0.f);
            float v2 = fmaxf(fmaf(xv, wr[l + 128], br[l + 128]), 0.f);
            float s = v0 + v1 + v2;
            float q = v0 * v0 + v1 * v1 + v2 * v2;
            #pragma unroll
            for (int o = 1; o < 64; o <<= 1) { s += __shfl_xor(s, o); q += __shfl_xor(q, o); }
            const float m   = s * (1.f / D_SZ);
            const float var = fmaxf(q * (1.f / D_SZ) - m * m, 0.f);
            const float rs  = rsqrtf(var + 1e-5f);
            xeT[xet_off(l,       c)] = f2b((v0 - m) * rs * lw0 + lb0);
            xeT[xet_off(l + 64,  c)] = f2b((v1 - m) * rs * lw1 + lb1);
            xeT[xet_off(l + 128, c)] = f2b((v2 - m) * rs * lw2 + lb2);
        }
        // zero-pad columns c in [100,128) (K-pad for G3)
        for (int idx = tid; idx < D_SZ * 28; idx += 512)
            xeT[xet_off(idx / 28, C_SZ + (idx % 28))] = 0;
    }
    __syncthreads();

    for (int chunk = 0; chunk < NCH; ++chunk) {
        const int pbase = chunk * CH;

        // ---- stage prev chunk -> ylds as packed hi/lo (coalesced, converted ONCE) ----
        {
            const float* pc = prev + (bP + pbase) * D_SZ;   // 32*192 floats
            #pragma unroll
            for (int k = 0; k < 3; ++k) {
                const int idx = tid + k * 512;              // float4 index, 1536 total
                const float4 v = *(const float4*)(pc + idx * 4);
                uint4 u;
                u.x = packhl(v.x); u.y = packhl(v.y); u.z = packhl(v.z); u.w = packhl(v.w);
                const int row = idx / 48, q = idx % 48;
                const int phys = q ^ ((row & 7) << 1);
                *(uint4*)(ylds + row * 192 + phys * 4) = u;
            }
        }
        __syncthreads();

        // ---- G1: y[32][192] = prev @ W2 (+cp), hi/lo split bf16 MFMA ----
        {
            const int wm = w >> 2, wn = w & 3;    // 2M x 4N: wave tile 16 x 48
            f32x4 acc[3] = {fzero, fzero, fzero};
            const int arow = 16 * wm + l15;
            const int rsw = (arow & 7) << 1;
            for (int kt = 0; kt < 6; ++kt) {
                const int e0 = kt * 32 + koff;
                const uint_t* ap = ylds + arow * 192 + (((e0 >> 2) ^ rsw) << 2);
                const uint4 u0 = *(const uint4*)ap;
                const uint4 u1 = *(const uint4*)(ap + 4);
                const uint_t uu[8] = {u0.x, u0.y, u0.z, u0.w, u1.x, u1.y, u1.z, u1.w};
                bf16x8 ah, al;
                #pragma unroll
                for (int j = 0; j < 8; ++j) {
                    ah[j] = (short)(uu[j] >> 16);
                    al[j] = (short)(uu[j] & 0xffffu);
                }
                #pragma unroll
                for (int nt = 0; nt < 3; ++nt) {
                    const int drow = 48 * wn + 16 * nt + l15;
                    const bf16x8 bh = *(const bf16x8*)(g_w2t_hi + drow * D_SZ + e0);
                    const bf16x8 bl = *(const bf16x8*)(g_w2t_lo + drow * D_SZ + e0);
                    acc[nt] = MFMA16(ah, bh, acc[nt], 0, 0, 0);
                    acc[nt] = MFMA16(al, bh, acc[nt], 0, 0, 0);
                    acc[nt] = MFMA16(ah, bl, acc[nt], 0, 0, 0);
                }
            }
            __syncthreads();   // all prev-reads done before overwriting ylds with y
            const int pr0 = 16 * wm + 4 * (l >> 4);
            #pragma unroll
            for (int nt = 0; nt < 3; ++nt) {
                const int d = 48 * wn + 16 * nt + l15;
                #pragma unroll
                for (int r = 0; r < 4; ++r) {
                    const int pl = pr0 + r;
                    const float y = acc[nt][r] + g_cp[(pbase + pl) * D_SZ + d];
                    ylds[y_off(pl, d)] = packhl(y);
                }
            }
        }
        __syncthreads();

        // ---- G2: s[32][128] = y @ col^T, hi/lo split both operands ----
        {
            const int wm2 = w >> 2, wn2 = w & 3;   // 2M x 4N: wave tile 16 x 32
            f32x4 sacc[2] = {fzero, fzero};
            const int prow = 16 * wm2 + l15;
            const int rsw = (prow & 7) << 1;
            for (int kt = 0; kt < 6; ++kt) {
                const int dk = kt * 32 + koff;
                const uint_t* yp = ylds + prow * 192 + (((dk >> 2) ^ rsw) << 2);
                const uint4 u0 = *(const uint4*)yp;
                const uint4 u1 = *(const uint4*)(yp + 4);
                const uint_t uu[8] = {u0.x, u0.y, u0.z, u0.w, u1.x, u1.y, u1.z, u1.w};
                bf16x8 ah, al;
                #pragma unroll
                for (int j = 0; j < 8; ++j) {
                    ah[j] = (short)(uu[j] >> 16);
                    al[j] = (short)(uu[j] & 0xffffu);
                }
                #pragma unroll
                for (int nt = 0; nt < 2; ++nt) {
                    const int crow = 32 * wn2 + 16 * nt + l15;
                    const bf16x8 bh = *(const bf16x8*)(g_colb_hi + crow * D_SZ + dk);
                    const bf16x8 bl = *(const bf16x8*)(g_colb_lo + crow * D_SZ + dk);
                    sacc[nt] = MFMA16(ah, bh, sacc[nt], 0, 0, 0);
                    sacc[nt] = MFMA16(al, bh, sacc[nt], 0, 0, 0);
                    sacc[nt] = MFMA16(ah, bl, sacc[nt], 0, 0, 0);
                }
            }
            __syncthreads();   // all y reads done before overwriting as smat
            const int pr0 = 16 * wm2 + 4 * (l >> 4);
            #pragma unroll
            for (int nt = 0; nt < 2; ++nt) {
                const int cc = 32 * wn2 + 16 * nt + l15;
                #pragma unroll
                for (int r = 0; r < 4; ++r)
                    smat[(pr0 + r) * 128 + cc] = sacc[nt][r];
            }
        }
        __syncthreads();

        // ---- softmax over c (4 rows/wave) -> maskb bf16 (swizzled), pad c>=100 -> 0 ----
        {
            #pragma unroll
            for (int i = 0; i < 4; ++i) {
                const int p = w * 4 + i;
                const float s0 = smat[p * 128 + l];
                const bool c1ok = (l < C_SZ - 64);
                const float s1 = c1ok ? smat[p * 128 + 64 + l] : -3.0e38f;
                float mx = fmaxf(s0, s1);
                #pragma unroll
                for (int o = 1; o < 64; o <<= 1) mx = fmaxf(mx, __shfl_xor(mx, o));
                const float e0 = __expf(s0 - mx);
                const float e1 = c1ok ? __expf(s1 - mx) : 0.f;
                float ts = e0 + e1;
                #pragma unroll
                for (int o = 1; o < 64; o <<= 1) ts += __shfl_xor(ts, o);
                const float inv = 1.f / ts;
                maskb[mb_off(p, l)] = f2b(e0 * inv);
                maskb[mb_off(p, 64 + l)] = c1ok ? f2b(e1 * inv) : (ushort_t)0;
            }
        }
        __syncthreads();

        // ---- G3: agg[32][192] = mask @ x_emb (K=128 padded), + epilogue store ----
        {
            const int wm3 = w >> 2, wn3 = w & 3;   // 2M x 4N: wave tile 16 x 48
            f32x4 acc[3] = {fzero, fzero, fzero};
            const int arow = 16 * wm3 + l15;
            const int rswa = (arow & 7) << 1;
            for (int kt = 0; kt < 4; ++kt) {
                const int c0 = kt * 32 + koff;
                const bf16x8 a = *(const bf16x8*)(maskb + arow * 128 +
                                                  ((((c0 >> 3) ^ rswa) & 15) << 3));
                #pragma unroll
                for (int nt = 0; nt < 3; ++nt) {
                    const int d = 48 * wn3 + 16 * nt + l15;
                    const bf16x8 bx = *(const bf16x8*)(xeT + d * 128 +
                                                       (((c0 >> 3) ^ ((d & 7) << 1)) << 3));
                    acc[nt] = MFMA16(a, bx, acc[nt], 0, 0, 0);
                }
            }
            const int pr0 = pbase + 16 * wm3 + 4 * (l >> 4);
            #pragma unroll
            for (int r = 0; r < 4; ++r) {
                const int p = pr0 + r;
                const float sc = 1.f + wexp[p];
                const float bi = bexp[p];
                float* orow = out + (bP + p) * D_SZ;
                #pragma unroll
                for (int nt = 0; nt < 3; ++nt) {
                    const int d = 48 * wn3 + 16 * nt + l15;
                    orow[d] = fmaf(acc[nt][r], sc, bi);
                }
            }
        }
        __syncthreads();   // protect ylds/maskb for next chunk's staging
    }
}

extern "C" void kernel_launch(void* const* d_in, const int* in_sizes, int n_in,
                              void* d_out, int out_size, void* d_ws, size_t ws_size,
                              hipStream_t stream) {
    const float* x           = (const float*)d_in[0];
    const float* prev        = (const float*)d_in[1];
    const float* wfe         = (const float*)d_in[2];
    const float* bfe         = (const float*)d_in[3];
    const float* ln_emb_w    = (const float*)d_in[4];
    const float* ln_emb_b    = (const float*)d_in[5];
    const float* ln_col_w    = (const float*)d_in[6];
    const float* ln_col_b    = (const float*)d_in[7];
    const float* ln_prompt_w = (const float*)d_in[8];
    const float* ln_prompt_b = (const float*)d_in[9];
    const float* W_imp       = (const float*)d_in[10];
    const float* b_imp       = (const float*)d_in[11];
    const float* emb_column  = (const float*)d_in[12];
    const float* emb_prompt  = (const float*)d_in[13];
    const float* wexp        = (const float*)d_in[14];
    const float* bexp        = (const float*)d_in[15];
    float* out = (float*)d_out;
    (void)d_ws; (void)ws_size;

    precompute<<<2 * P_SZ + 48, 192, 0, stream>>>(emb_column, emb_prompt,
        ln_col_w, ln_col_b, ln_prompt_w, ln_prompt_b, W_imp, b_imp);
    fused<<<B_SZ, 512, 0, stream>>>(x, prev, wfe, bfe, ln_emb_w, ln_emb_b,
        wexp, bexp, out);
}